// Round 6
// baseline (289.701 us; speedup 1.0000x reference)
//
#include <hip/hip_runtime.h>
#include <hip/hip_bf16.h>

#define Bn 8
#define Nn 4096
#define Cn 1024
#define Dn 512
#define Mn 64

typedef __hip_bfloat16 bf16;
typedef __attribute__((ext_vector_type(8))) short short8;
typedef __attribute__((ext_vector_type(4))) short short4x;
typedef __attribute__((ext_vector_type(4))) float f32x4;

#define MFMA16(a, b, c) __builtin_amdgcn_mfma_f32_16x16x32_bf16((a), (b), (c), 0, 0, 0)

__device__ inline short bfbits(float f) {
  union { bf16 b; short s; } u;
  u.b = __float2bfloat16(f);
  return u.s;
}
__device__ inline float bfval(short s) {
  union { short s; bf16 b; } u;
  u.s = s;
  return __bfloat162float(u.b);
}

// ---------------------------------------------------------------------------
// K0: V[m][c] = sum_d av[m][d]*W[d][c]  (bf16 hi+lo);  c0[m] = av[m,:].bias
// grid (Mn, Cn/64) = 1024 blocks, block 256  [verified]
// ---------------------------------------------------------------------------
__global__ __launch_bounds__(256) void prep_kernel(
    const float* __restrict__ W, const float* __restrict__ bias,
    const float* __restrict__ av, bf16* __restrict__ Vhi,
    bf16* __restrict__ Vlo, float* __restrict__ c0) {
  const int m = blockIdx.x;
  const int t = threadIdx.x;
  const int cl = t & 63, dg = t >> 6;
  const int c = blockIdx.y * 64 + cl;
  const float* wp = W + (size_t)(dg * 128) * Cn + c;
  const float* ap = av + m * Dn + dg * 128;
  float a0 = 0.f, a1 = 0.f, a2 = 0.f, a3 = 0.f;
#pragma unroll 8
  for (int i = 0; i < 128; i += 4) {
    a0 = fmaf(ap[i + 0], wp[(size_t)(i + 0) * Cn], a0);
    a1 = fmaf(ap[i + 1], wp[(size_t)(i + 1) * Cn], a1);
    a2 = fmaf(ap[i + 2], wp[(size_t)(i + 2) * Cn], a2);
    a3 = fmaf(ap[i + 3], wp[(size_t)(i + 3) * Cn], a3);
  }
  __shared__ float red[256];
  red[t] = (a0 + a1) + (a2 + a3);
  __syncthreads();
  const float v = red[cl] + red[cl + 64] + red[cl + 128] + red[cl + 192];
  if (dg == 0) {
    const bf16 hi = __float2bfloat16(v);
    Vhi[m * Cn + c] = hi;
    Vlo[m * Cn + c] = __float2bfloat16(v - __bfloat162float(hi));
  }
  if (blockIdx.y == 0) {
    __syncthreads();
    red[t] = av[m * Dn + t] * bias[t] + av[m * Dn + t + 256] * bias[t + 256];
    __syncthreads();
    if (t < 64) {
      float s = red[t] + red[t + 64] + red[t + 128] + red[t + 192];
#pragma unroll
      for (int off = 32; off > 0; off >>= 1) s += __shfl_down(s, off);
      if (t == 0) c0[m] = s;
    }
  }
}

// ---------------------------------------------------------------------------
// K1: logits tile (64n x 64m) + LOCAL softmax, BARRIER-FREE main loop.
// X staged in LDS before was only read back by the staging wave -> convert
// in registers instead.  V (256KB hi+lo) is shared by ALL blocks -> L2-hot,
// B-frags loaded directly from global.  x prefetched 2 chunks (256k) deep.
// Epilogue (R4-verified): per-64n-group Mp/Sp, unnormalized bf16 wgt.
// grid (Nn/64, Bn) = 512, block 256 (4 indep waves), LDS 2KB.
// ---------------------------------------------------------------------------
__global__ __launch_bounds__(256, 2) void logits_sm_kernel(
    const float* __restrict__ x, const bf16* __restrict__ Vhi,
    const bf16* __restrict__ Vlo, const float* __restrict__ c0,
    bf16* __restrict__ wgt, float* __restrict__ Mp, float* __restrict__ Sp) {
  const int g = blockIdx.x;  // n-group (64 per b)
  const int n0 = g * 64;
  const int b = blockIdx.y;
  const int t = threadIdx.x;
  const int w = t >> 6, lane = t & 63, lr = lane & 15, q = lane >> 4;

  const float* xrow = x + (size_t)(b * Nn + n0 + w * 16 + lr) * Cn + q * 8;
  const bf16* vh = Vhi + (size_t)lr * Cn + q * 8;
  const bf16* vl = Vlo + (size_t)lr * Cn + q * 8;

  f32x4 acc[4];
#pragma unroll
  for (int i = 0; i < 4; ++i) acc[i] = (f32x4){0.f, 0.f, 0.f, 0.f};

  // 2-chunk-deep x prefetch: xa = current chunk, xb = +128, xc = +256
  float4 xa0[4], xa1[4], xb0[4], xb1[4], xc0[4], xc1[4];
#pragma unroll
  for (int s = 0; s < 4; ++s) {
    xa0[s] = *(const float4*)(xrow + s * 32);
    xa1[s] = *(const float4*)(xrow + s * 32 + 4);
    xb0[s] = *(const float4*)(xrow + 128 + s * 32);
    xb1[s] = *(const float4*)(xrow + 128 + s * 32 + 4);
    xc0[s] = xb0[s]; xc1[s] = xb1[s];
  }

  for (int kc = 0; kc < Cn; kc += 128) {
    if (kc + 256 < Cn) {
#pragma unroll
      for (int s = 0; s < 4; ++s) {
        xc0[s] = *(const float4*)(xrow + kc + 256 + s * 32);
        xc1[s] = *(const float4*)(xrow + kc + 256 + s * 32 + 4);
      }
    }
#pragma unroll
    for (int s = 0; s < 4; ++s) {
      const int kk = kc + s * 32;
      short8 a;
      a[0] = bfbits(xa0[s].x); a[1] = bfbits(xa0[s].y);
      a[2] = bfbits(xa0[s].z); a[3] = bfbits(xa0[s].w);
      a[4] = bfbits(xa1[s].x); a[5] = bfbits(xa1[s].y);
      a[6] = bfbits(xa1[s].z); a[7] = bfbits(xa1[s].w);
#pragma unroll
      for (int mt = 0; mt < 4; ++mt) {
        acc[mt] = MFMA16(a, *(const short8*)(vh + (size_t)(mt * 16) * Cn + kk), acc[mt]);
        acc[mt] = MFMA16(a, *(const short8*)(vl + (size_t)(mt * 16) * Cn + kk), acc[mt]);
      }
    }
#pragma unroll
    for (int s = 0; s < 4; ++s) {
      xa0[s] = xb0[s]; xa1[s] = xb1[s];
      xb0[s] = xc0[s]; xb1[s] = xc1[s];
    }
  }

  // ---- local softmax epilogue (D layout: row n=q*4+reg, col m=lr) ----
  __shared__ float wredM[256];  // [wave][m]
  __shared__ float wredS[256];
  float rmax[4];
#pragma unroll
  for (int mt = 0; mt < 4; ++mt) {
    float r = fmaxf(fmaxf(acc[mt][0], acc[mt][1]), fmaxf(acc[mt][2], acc[mt][3]));
    r = fmaxf(r, __shfl_xor(r, 16));
    r = fmaxf(r, __shfl_xor(r, 32));
    rmax[mt] = r;
  }
  if (q == 0)
#pragma unroll
    for (int mt = 0; mt < 4; ++mt) wredM[w * 64 + mt * 16 + lr] = rmax[mt];
  __syncthreads();
  float vv[4][4];
#pragma unroll
  for (int mt = 0; mt < 4; ++mt) {
    const int m = mt * 16 + lr;
    const float mp = fmaxf(fmaxf(wredM[m], wredM[64 + m]),
                           fmaxf(wredM[128 + m], wredM[192 + m]));
    float s = 0.f;
#pragma unroll
    for (int r = 0; r < 4; ++r) {
      vv[mt][r] = __expf(acc[mt][r] - mp);
      s += vv[mt][r];
    }
    s += __shfl_xor(s, 16);
    s += __shfl_xor(s, 32);
    if (q == 0) wredS[w * 64 + m] = s;
  }
#pragma unroll
  for (int mt = 0; mt < 4; ++mt) {  // unnormalized weights out
    const int m = mt * 16 + lr;
    short4x o;
    o[0] = bfbits(vv[mt][0]); o[1] = bfbits(vv[mt][1]);
    o[2] = bfbits(vv[mt][2]); o[3] = bfbits(vv[mt][3]);
    *(short4x*)&wgt[(size_t)(b * Mn + m) * Nn + n0 + w * 16 + q * 4] = o;
  }
  __syncthreads();
  if (w == 0) {  // lane = m
    const int m = lane;
    const float mp = fmaxf(fmaxf(wredM[m], wredM[64 + m]),
                           fmaxf(wredM[128 + m], wredM[192 + m]));
    const float sp = wredS[m] + wredS[64 + m] + wredS[128 + m] + wredS[192 + m];
    Mp[((size_t)b * Mn + m) * 64 + g] = mp + c0[m];  // fold bias into stored max
    Sp[((size_t)b * Mn + m) * 64 + g] = sp;
  }
}

// ---------------------------------------------------------------------------
// K1.5: normalize wgt in place: global M,S per (b,m) row from Mp/Sp, then
// wgt[n] *= e^{Mp[g(n)]-M}/S.  8MB traffic, L2-hot metadata.
// grid Bn*Mn = 512, block 256 (each thread: 16 contiguous n = one group slice)
// ---------------------------------------------------------------------------
__global__ __launch_bounds__(256) void norm_kernel(
    bf16* __restrict__ wgt, const float* __restrict__ Mp,
    const float* __restrict__ Sp) {
  const int row = blockIdx.x;  // b*Mn + m
  const int t = threadIdx.x;
  __shared__ float sMS[2];
  if (t < 64) {
    const float mp = Mp[(size_t)row * 64 + t];
    const float sp = Sp[(size_t)row * 64 + t];
    float M = mp;
#pragma unroll
    for (int off = 32; off > 0; off >>= 1) M = fmaxf(M, __shfl_xor(M, off));
    float e = __expf(mp - M) * sp;
#pragma unroll
    for (int off = 32; off > 0; off >>= 1) e += __shfl_xor(e, off);
    if (t == 0) { sMS[0] = M; sMS[1] = e; }
  }
  __syncthreads();
  const float M = sMS[0], inv = 1.f / sMS[1];
  const float sc = __expf(Mp[(size_t)row * 64 + (t >> 2)] - M) * inv;
  bf16* wp = wgt + (size_t)row * Nn + t * 16;
  short8 u0 = *(const short8*)(wp);
  short8 u1 = *(const short8*)(wp + 8);
  short8 o0, o1;
#pragma unroll
  for (int j = 0; j < 8; ++j) {
    o0[j] = bfbits(bfval(u0[j]) * sc);
    o1[j] = bfbits(bfval(u1[j]) * sc);
  }
  *(short8*)(wp) = o0;
  *(short8*)(wp + 8) = o1;
}

// ---------------------------------------------------------------------------
// K2: part[ks][b][m][c] = sum_{k-eighth} wgt[b][m][k]*x[b][k][c]
// z=8 split -> 1024 blocks = 4 blocks/CU = 16 waves/CU.  XT double-buffered
// (ONE barrier per 128-k chunk).  Staging/swizzle identical to verified pool.
// grid (Cn/64, Bn, 8), block 256, LDS 34.8KB.
// ---------------------------------------------------------------------------
__global__ __launch_bounds__(256, 4) void pool_kernel(
    const float* __restrict__ x, const bf16* __restrict__ wgt,
    float* __restrict__ part) {
  const int cbase = blockIdx.x * 64;
  const int b = blockIdx.y;
  const int ks = blockIdx.z;
  const int t = threadIdx.x;
  __shared__ short XT[2][64][136];  // [buf][c][k-swizzled]
  const int w = t >> 6, lane = t & 63, lr = lane & 15, q = lane >> 4;
  const int mh = (w & 1) * 32, ch = (w >> 1) * 32;
  f32x4 acc[2][2];
#pragma unroll
  for (int i = 0; i < 2; ++i)
#pragma unroll
    for (int j = 0; j < 2; ++j) acc[i][j] = (f32x4){0.f, 0.f, 0.f, 0.f};

  const int h = t & 15, g = t >> 4;
  const int swz = 8 * (h & 7);
  const int swzr0 = 8 * (((ch + lr) >> 2) & 7);
  const int swzr1 = 8 * (((ch + 16 + lr) >> 2) & 7);
  const int NQ = Nn / 8;
  const int kbase = ks * NQ;
  const float* xsrc = x + (size_t)b * Nn * Cn + (size_t)(kbase + 4 * g) * Cn + cbase + 4 * h;
  const bf16* wr0 = wgt + (size_t)(b * Mn + mh + lr) * Nn + kbase;
  const bf16* wr1 = wr0 + (size_t)16 * Nn;

  float4 pf[8];
#pragma unroll
  for (int i = 0; i < 4; ++i) {  // chunk 0
    pf[i]     = *(const float4*)(xsrc + (size_t)i * Cn);
    pf[4 + i] = *(const float4*)(xsrc + (size_t)(64 + i) * Cn);
  }
  // stage chunk 0 into XT[0]
#pragma unroll
  for (int blk = 0; blk < 2; ++blk) {
    const float4 r0 = pf[blk * 4 + 0], r1 = pf[blk * 4 + 1];
    const float4 r2 = pf[blk * 4 + 2], r3 = pf[blk * 4 + 3];
    const int kof = (blk * 64 + 4 * g) ^ swz;
    short4x v0, v1, v2, v3;
    v0[0] = bfbits(r0.x); v0[1] = bfbits(r1.x); v0[2] = bfbits(r2.x); v0[3] = bfbits(r3.x);
    v1[0] = bfbits(r0.y); v1[1] = bfbits(r1.y); v1[2] = bfbits(r2.y); v1[3] = bfbits(r3.y);
    v2[0] = bfbits(r0.z); v2[1] = bfbits(r1.z); v2[2] = bfbits(r2.z); v2[3] = bfbits(r3.z);
    v3[0] = bfbits(r0.w); v3[1] = bfbits(r1.w); v3[2] = bfbits(r2.w); v3[3] = bfbits(r3.w);
    *(short4x*)&XT[0][4 * h + 0][kof] = v0;
    *(short4x*)&XT[0][4 * h + 1][kof] = v1;
    *(short4x*)&XT[0][4 * h + 2][kof] = v2;
    *(short4x*)&XT[0][4 * h + 3][kof] = v3;
  }
#pragma unroll
  for (int i = 0; i < 4; ++i) {  // chunk 1 prefetch
    pf[i]     = *(const float4*)(xsrc + (size_t)(128 + i) * Cn);
    pf[4 + i] = *(const float4*)(xsrc + (size_t)(192 + i) * Cn);
  }

  int cur = 0;
  for (int kc = 0; kc < NQ; kc += 128, cur ^= 1) {
    __syncthreads();  // XT[cur] fully staged; all waves done reading XT[cur^1]
    if (kc + 128 < NQ) {  // stage chunk kc+128 into XT[cur^1]
#pragma unroll
      for (int blk = 0; blk < 2; ++blk) {
        const float4 r0 = pf[blk * 4 + 0], r1 = pf[blk * 4 + 1];
        const float4 r2 = pf[blk * 4 + 2], r3 = pf[blk * 4 + 3];
        const int kof = (blk * 64 + 4 * g) ^ swz;
        short4x v0, v1, v2, v3;
        v0[0] = bfbits(r0.x); v0[1] = bfbits(r1.x); v0[2] = bfbits(r2.x); v0[3] = bfbits(r3.x);
        v1[0] = bfbits(r0.y); v1[1] = bfbits(r1.y); v1[2] = bfbits(r2.y); v1[3] = bfbits(r3.y);
        v2[0] = bfbits(r0.z); v2[1] = bfbits(r1.z); v2[2] = bfbits(r2.z); v2[3] = bfbits(r3.z);
        v3[0] = bfbits(r0.w); v3[1] = bfbits(r1.w); v3[2] = bfbits(r2.w); v3[3] = bfbits(r3.w);
        *(short4x*)&XT[cur ^ 1][4 * h + 0][kof] = v0;
        *(short4x*)&XT[cur ^ 1][4 * h + 1][kof] = v1;
        *(short4x*)&XT[cur ^ 1][4 * h + 2][kof] = v2;
        *(short4x*)&XT[cur ^ 1][4 * h + 3][kof] = v3;
      }
      if (kc + 256 < NQ) {  // prefetch chunk kc+256
#pragma unroll
        for (int i = 0; i < 4; ++i) {
          pf[i]     = *(const float4*)(xsrc + (size_t)(kc + 256 + i) * Cn);
          pf[4 + i] = *(const float4*)(xsrc + (size_t)(kc + 320 + i) * Cn);
        }
      }
    }
#pragma unroll
    for (int kk = 0; kk < 128; kk += 32) {
      const short8 a0 = *(const short8*)(wr0 + kc + kk + q * 8);
      const short8 a1 = *(const short8*)(wr1 + kc + kk + q * 8);
      const short8 b0 = *(const short8*)&XT[cur][ch + lr][(kk + q * 8) ^ swzr0];
      const short8 b1 = *(const short8*)&XT[cur][ch + 16 + lr][(kk + q * 8) ^ swzr1];
      acc[0][0] = MFMA16(a0, b0, acc[0][0]);
      acc[0][1] = MFMA16(a0, b1, acc[0][1]);
      acc[1][0] = MFMA16(a1, b0, acc[1][0]);
      acc[1][1] = MFMA16(a1, b1, acc[1][1]);
    }
  }
  float* pout = part + ((size_t)ks * Bn + b) * Mn * Cn;
#pragma unroll
  for (int mi = 0; mi < 2; ++mi)
#pragma unroll
    for (int ci = 0; ci < 2; ++ci) {
      const int m = mh + mi * 16 + q * 4;
      const int c = cbase + ch + ci * 16 + lr;
#pragma unroll
      for (int reg = 0; reg < 4; ++reg)
        pout[(size_t)(m + reg) * Cn + c] = acc[mi][ci][reg];
    }
}

// ---------------------------------------------------------------------------
// K3: out = sum of 8 partials (float4).  grid 512, block 256
// ---------------------------------------------------------------------------
__global__ __launch_bounds__(256) void reduce_kernel(
    const float* __restrict__ part, float* __restrict__ out) {
  const int i = blockIdx.x * 256 + threadIdx.x;
  const float4* p = (const float4*)part;
  const int S4 = (Bn * Mn * Cn) / 4;
  float4 o = (float4){0.f, 0.f, 0.f, 0.f};
#pragma unroll
  for (int j = 0; j < 8; ++j) {
    const float4 v = p[i + j * S4];
    o.x += v.x; o.y += v.y; o.z += v.z; o.w += v.w;
  }
  ((float4*)out)[i] = o;
}

extern "C" void kernel_launch(void* const* d_in, const int* in_sizes, int n_in,
                              void* d_out, int out_size, void* d_ws, size_t ws_size,
                              hipStream_t stream) {
  const float* x = (const float*)d_in[0];
  const float* W = (const float*)d_in[1];
  const float* bias = (const float*)d_in[2];
  const float* av = (const float*)d_in[3];
  float* out = (float*)d_out;
  char* ws = (char*)d_ws;

  bf16* Vhi = (bf16*)(ws + 0);           // 131072 B
  bf16* Vlo = (bf16*)(ws + 131072);      // 131072 B
  float* c0 = (float*)(ws + 262144);     // 1024 B
  bf16* wgt = (bf16*)(ws + 263168);      // 4194304 B
  float* Mp = (float*)(ws + 4457472);    // 131072 B
  float* Sp = (float*)(ws + 4588544);    // 131072 B
  float* part = (float*)(ws + 4719616);  // 8 x 2097152 B  (total ~21.5 MB)

  prep_kernel<<<dim3(Mn, Cn / 64), 256, 0, stream>>>(W, bias, av, Vhi, Vlo, c0);
  logits_sm_kernel<<<dim3(Nn / 64, Bn), 256, 0, stream>>>(x, Vhi, Vlo, c0, wgt, Mp, Sp);
  norm_kernel<<<Bn * Mn, 256, 0, stream>>>(wgt, Mp, Sp);
  pool_kernel<<<dim3(Cn / 64, Bn, 8), 256, 0, stream>>>(x, wgt, part);
  reduce_kernel<<<(Bn * Mn * Cn) / 1024, 256, 0, stream>>>(part, out);
}

// Round 7
// 254.835 us; speedup vs baseline: 1.1368x; 1.1368x over previous
//
#include <hip/hip_runtime.h>
#include <hip/hip_bf16.h>

#define Bn 8
#define Nn 4096
#define Cn 1024
#define Dn 512
#define Mn 64

typedef __hip_bfloat16 bf16;
typedef __attribute__((ext_vector_type(8))) short short8;
typedef __attribute__((ext_vector_type(4))) short short4x;
typedef __attribute__((ext_vector_type(4))) float f32x4;

#define MFMA16(a, b, c) __builtin_amdgcn_mfma_f32_16x16x32_bf16((a), (b), (c), 0, 0, 0)

__device__ inline short bfbits(float f) {
  union { bf16 b; short s; } u;
  u.b = __float2bfloat16(f);
  return u.s;
}

// ---------------------------------------------------------------------------
// K0: V[m][c] = sum_d av[m][d]*W[d][c]  (bf16 hi+lo);  c0[m] = av[m,:].bias
// grid (Mn, Cn/64) = 1024 blocks, block 256  [R1-verified]
// ---------------------------------------------------------------------------
__global__ __launch_bounds__(256) void prep_kernel(
    const float* __restrict__ W, const float* __restrict__ bias,
    const float* __restrict__ av, bf16* __restrict__ Vhi,
    bf16* __restrict__ Vlo, float* __restrict__ c0) {
  const int m = blockIdx.x;
  const int t = threadIdx.x;
  const int cl = t & 63, dg = t >> 6;
  const int c = blockIdx.y * 64 + cl;
  const float* wp = W + (size_t)(dg * 128) * Cn + c;
  const float* ap = av + m * Dn + dg * 128;
  float a0 = 0.f, a1 = 0.f, a2 = 0.f, a3 = 0.f;
#pragma unroll 8
  for (int i = 0; i < 128; i += 4) {
    a0 = fmaf(ap[i + 0], wp[(size_t)(i + 0) * Cn], a0);
    a1 = fmaf(ap[i + 1], wp[(size_t)(i + 1) * Cn], a1);
    a2 = fmaf(ap[i + 2], wp[(size_t)(i + 2) * Cn], a2);
    a3 = fmaf(ap[i + 3], wp[(size_t)(i + 3) * Cn], a3);
  }
  __shared__ float red[256];
  red[t] = (a0 + a1) + (a2 + a3);
  __syncthreads();
  const float v = red[cl] + red[cl + 64] + red[cl + 128] + red[cl + 192];
  if (dg == 0) {
    const bf16 hi = __float2bfloat16(v);
    Vhi[m * Cn + c] = hi;
    Vlo[m * Cn + c] = __float2bfloat16(v - __bfloat162float(hi));
  }
  if (blockIdx.y == 0) {
    __syncthreads();
    red[t] = av[m * Dn + t] * bias[t] + av[m * Dn + t + 256] * bias[t + 256];
    __syncthreads();
    if (t < 64) {
      float s = red[t] + red[t + 64] + red[t + 128] + red[t + 192];
#pragma unroll
      for (int off = 32; off > 0; off >>= 1) s += __shfl_down(s, off);
      if (t == 0) c0[m] = s;
    }
  }
}

// ---------------------------------------------------------------------------
// K1: logits[b][m][n] = x[b][n][:].V[m][:] + c0[m]
// Hybrid of R1 (verified) and R6 findings:
//  - V (hi+lo) staged in LDS: it is the operand SHARED by all 4 waves and
//    scatter-prone from global (R6: 16 lines/load, L1 thrash -> 100us).
//    Double-buffered at BK=64 -> ONE barrier per chunk, staging overlaps MFMA.
//  - x stays in registers (only the owning wave reads its rows; 128-B
//    coalesced row segments), 2-chunk register prefetch.
// LDS 36.9KB (VsH+VsL, pad 72: stride 36dw -> 2-way banks, free).
// grid (Nn/64, Bn) = 512, block 256.
// ---------------------------------------------------------------------------
__global__ __launch_bounds__(256, 2) void logits_kernel(
    const float* __restrict__ x, const bf16* __restrict__ Vhi,
    const bf16* __restrict__ Vlo, const float* __restrict__ c0,
    float* __restrict__ logits) {
  const int n0 = blockIdx.x * 64;
  const int b = blockIdx.y;
  const int t = threadIdx.x;
  __shared__ short VsH[2][64][72];
  __shared__ short VsL[2][64][72];
  const int w = t >> 6, lane = t & 63, lr = lane & 15, q = lane >> 4;

  // x row pointer: row n0 + w*16 + lr, base col q*8
  const float* xrow = x + (size_t)(b * Nn + n0 + w * 16 + lr) * Cn + q * 8;

  // V staging map: thread t handles rows {t>>3, (t>>3)+32}, col (t&7)*8
  const int vr = t >> 3, vs = (t & 7) * 8;
  const bf16* vh0 = Vhi + (size_t)vr * Cn + vs;
  const bf16* vh1 = vh0 + (size_t)32 * Cn;
  const bf16* vl0 = Vlo + (size_t)vr * Cn + vs;
  const bf16* vl1 = vl0 + (size_t)32 * Cn;

  f32x4 acc[4];
#pragma unroll
  for (int i = 0; i < 4; ++i) acc[i] = (f32x4){0.f, 0.f, 0.f, 0.f};

  // --- prologue: stage V chunk 0 into buf 0; prefetch V chunk 1 to regs ---
  short8 ph0 = *(const short8*)(vh0);
  short8 ph1 = *(const short8*)(vh1);
  short8 pl0 = *(const short8*)(vl0);
  short8 pl1 = *(const short8*)(vl1);
  *(short8*)&VsH[0][vr][vs] = ph0;
  *(short8*)&VsH[0][vr + 32][vs] = ph1;
  *(short8*)&VsL[0][vr][vs] = pl0;
  *(short8*)&VsL[0][vr + 32][vs] = pl1;
  ph0 = *(const short8*)(vh0 + 64);
  ph1 = *(const short8*)(vh1 + 64);
  pl0 = *(const short8*)(vl0 + 64);
  pl1 = *(const short8*)(vl1 + 64);

  // --- x register prefetch, 2 chunks (128 k) deep ---
  float4 xa0[2], xa1[2], xb0[2], xb1[2], xc0[2], xc1[2];
#pragma unroll
  for (int s = 0; s < 2; ++s) {
    xa0[s] = *(const float4*)(xrow + s * 32);
    xa1[s] = *(const float4*)(xrow + s * 32 + 4);
    xb0[s] = *(const float4*)(xrow + 64 + s * 32);
    xb1[s] = *(const float4*)(xrow + 64 + s * 32 + 4);
    xc0[s] = xb0[s]; xc1[s] = xb1[s];
  }

  int cur = 0;
  for (int kc = 0; kc < Cn; kc += 64, cur ^= 1) {
    __syncthreads();  // Vs[cur] staged; all waves done reading Vs[cur^1]
    if (kc + 64 < Cn) {
      // write next V chunk (already in regs) into the other buffer
      *(short8*)&VsH[cur ^ 1][vr][vs] = ph0;
      *(short8*)&VsH[cur ^ 1][vr + 32][vs] = ph1;
      *(short8*)&VsL[cur ^ 1][vr][vs] = pl0;
      *(short8*)&VsL[cur ^ 1][vr + 32][vs] = pl1;
      if (kc + 128 < Cn) {  // prefetch V chunk kc+128
        ph0 = *(const short8*)(vh0 + kc + 128);
        ph1 = *(const short8*)(vh1 + kc + 128);
        pl0 = *(const short8*)(vl0 + kc + 128);
        pl1 = *(const short8*)(vl1 + kc + 128);
      }
    }
    if (kc + 128 < Cn) {  // x chunk kc+128 into regs
#pragma unroll
      for (int s = 0; s < 2; ++s) {
        xc0[s] = *(const float4*)(xrow + kc + 128 + s * 32);
        xc1[s] = *(const float4*)(xrow + kc + 128 + s * 32 + 4);
      }
    }
#pragma unroll
    for (int s = 0; s < 2; ++s) {
      short8 a;
      a[0] = bfbits(xa0[s].x); a[1] = bfbits(xa0[s].y);
      a[2] = bfbits(xa0[s].z); a[3] = bfbits(xa0[s].w);
      a[4] = bfbits(xa1[s].x); a[5] = bfbits(xa1[s].y);
      a[6] = bfbits(xa1[s].z); a[7] = bfbits(xa1[s].w);
#pragma unroll
      for (int mt = 0; mt < 4; ++mt) {
        acc[mt] = MFMA16(a, *(const short8*)&VsH[cur][mt * 16 + lr][s * 32 + q * 8], acc[mt]);
        acc[mt] = MFMA16(a, *(const short8*)&VsL[cur][mt * 16 + lr][s * 32 + q * 8], acc[mt]);
      }
    }
#pragma unroll
    for (int s = 0; s < 2; ++s) {  // rotate x pipeline
      xa0[s] = xb0[s]; xa1[s] = xb1[s];
      xb0[s] = xc0[s]; xb1[s] = xc1[s];
    }
  }
  // D layout: row(n)=q*4+reg, col(m)=lr  [m89-verified]
#pragma unroll
  for (int mt = 0; mt < 4; ++mt) {
    const int m = mt * 16 + lr;
    const float bb = c0[m];
    float4 o;
    o.x = acc[mt][0] + bb; o.y = acc[mt][1] + bb;
    o.z = acc[mt][2] + bb; o.w = acc[mt][3] + bb;
    *(float4*)&logits[(size_t)(b * Mn + m) * Nn + n0 + w * 16 + q * 4] = o;
  }
}

// ---------------------------------------------------------------------------
// K2: softmax over N per (b,m) row; bf16 weights out. grid Bn*Mn, block 256
// [R1-verified]
// ---------------------------------------------------------------------------
__global__ __launch_bounds__(256) void softmax_kernel(
    const float* __restrict__ logits, bf16* __restrict__ wgt) {
  const int row = blockIdx.x;
  const int t = threadIdx.x;
  const float* L = logits + (size_t)row * Nn;
  float v[16];
  float mx = -3.4e38f;
#pragma unroll
  for (int i = 0; i < 16; ++i) {
    v[i] = L[t + 256 * i];
    mx = fmaxf(mx, v[i]);
  }
#pragma unroll
  for (int off = 32; off > 0; off >>= 1) mx = fmaxf(mx, __shfl_down(mx, off));
  __shared__ float sred[4];
  if ((t & 63) == 0) sred[t >> 6] = mx;
  __syncthreads();
  mx = fmaxf(fmaxf(sred[0], sred[1]), fmaxf(sred[2], sred[3]));
  float sum = 0.f;
#pragma unroll
  for (int i = 0; i < 16; ++i) {
    v[i] = __expf(v[i] - mx);
    sum += v[i];
  }
#pragma unroll
  for (int off = 32; off > 0; off >>= 1) sum += __shfl_down(sum, off);
  __syncthreads();
  if ((t & 63) == 0) sred[t >> 6] = sum;
  __syncthreads();
  const float inv = 1.f / (sred[0] + sred[1] + sred[2] + sred[3]);
#pragma unroll
  for (int i = 0; i < 16; ++i)
    wgt[(size_t)row * Nn + t + 256 * i] = __float2bfloat16(v[i] * inv);
}

// ---------------------------------------------------------------------------
// K3: part[ks][b][m][c] = sum_{k-eighth} wgt[b][m][k]*x[b][k][c]
// z=8 -> 1024 blocks = 4 blocks/CU = 16 waves/CU.  XT double-buffered (one
// barrier per 128-k chunk).  [R6-verified]
// grid (Cn/64, Bn, 8), block 256, LDS 34.8KB.
// ---------------------------------------------------------------------------
__global__ __launch_bounds__(256, 4) void pool_kernel(
    const float* __restrict__ x, const bf16* __restrict__ wgt,
    float* __restrict__ part) {
  const int cbase = blockIdx.x * 64;
  const int b = blockIdx.y;
  const int ks = blockIdx.z;
  const int t = threadIdx.x;
  __shared__ short XT[2][64][136];  // [buf][c][k-swizzled]
  const int w = t >> 6, lane = t & 63, lr = lane & 15, q = lane >> 4;
  const int mh = (w & 1) * 32, ch = (w >> 1) * 32;
  f32x4 acc[2][2];
#pragma unroll
  for (int i = 0; i < 2; ++i)
#pragma unroll
    for (int j = 0; j < 2; ++j) acc[i][j] = (f32x4){0.f, 0.f, 0.f, 0.f};

  const int h = t & 15, g = t >> 4;
  const int swz = 8 * (h & 7);
  const int swzr0 = 8 * (((ch + lr) >> 2) & 7);
  const int swzr1 = 8 * (((ch + 16 + lr) >> 2) & 7);
  const int NQ = Nn / 8;
  const int kbase = ks * NQ;
  const float* xsrc = x + (size_t)b * Nn * Cn + (size_t)(kbase + 4 * g) * Cn + cbase + 4 * h;
  const bf16* wr0 = wgt + (size_t)(b * Mn + mh + lr) * Nn + kbase;
  const bf16* wr1 = wr0 + (size_t)16 * Nn;

  float4 pf[8];
#pragma unroll
  for (int i = 0; i < 4; ++i) {  // chunk 0
    pf[i]     = *(const float4*)(xsrc + (size_t)i * Cn);
    pf[4 + i] = *(const float4*)(xsrc + (size_t)(64 + i) * Cn);
  }
  // stage chunk 0 into XT[0]
#pragma unroll
  for (int blk = 0; blk < 2; ++blk) {
    const float4 r0 = pf[blk * 4 + 0], r1 = pf[blk * 4 + 1];
    const float4 r2 = pf[blk * 4 + 2], r3 = pf[blk * 4 + 3];
    const int kof = (blk * 64 + 4 * g) ^ swz;
    short4x v0, v1, v2, v3;
    v0[0] = bfbits(r0.x); v0[1] = bfbits(r1.x); v0[2] = bfbits(r2.x); v0[3] = bfbits(r3.x);
    v1[0] = bfbits(r0.y); v1[1] = bfbits(r1.y); v1[2] = bfbits(r2.y); v1[3] = bfbits(r3.y);
    v2[0] = bfbits(r0.z); v2[1] = bfbits(r1.z); v2[2] = bfbits(r2.z); v2[3] = bfbits(r3.z);
    v3[0] = bfbits(r0.w); v3[1] = bfbits(r1.w); v3[2] = bfbits(r2.w); v3[3] = bfbits(r3.w);
    *(short4x*)&XT[0][4 * h + 0][kof] = v0;
    *(short4x*)&XT[0][4 * h + 1][kof] = v1;
    *(short4x*)&XT[0][4 * h + 2][kof] = v2;
    *(short4x*)&XT[0][4 * h + 3][kof] = v3;
  }
#pragma unroll
  for (int i = 0; i < 4; ++i) {  // chunk 1 prefetch
    pf[i]     = *(const float4*)(xsrc + (size_t)(128 + i) * Cn);
    pf[4 + i] = *(const float4*)(xsrc + (size_t)(192 + i) * Cn);
  }

  int cur = 0;
  for (int kc = 0; kc < NQ; kc += 128, cur ^= 1) {
    __syncthreads();  // XT[cur] fully staged; all waves done reading XT[cur^1]
    if (kc + 128 < NQ) {  // stage chunk kc+128 into XT[cur^1]
#pragma unroll
      for (int blk = 0; blk < 2; ++blk) {
        const float4 r0 = pf[blk * 4 + 0], r1 = pf[blk * 4 + 1];
        const float4 r2 = pf[blk * 4 + 2], r3 = pf[blk * 4 + 3];
        const int kof = (blk * 64 + 4 * g) ^ swz;
        short4x v0, v1, v2, v3;
        v0[0] = bfbits(r0.x); v0[1] = bfbits(r1.x); v0[2] = bfbits(r2.x); v0[3] = bfbits(r3.x);
        v1[0] = bfbits(r0.y); v1[1] = bfbits(r1.y); v1[2] = bfbits(r2.y); v1[3] = bfbits(r3.y);
        v2[0] = bfbits(r0.z); v2[1] = bfbits(r1.z); v2[2] = bfbits(r2.z); v2[3] = bfbits(r3.z);
        v3[0] = bfbits(r0.w); v3[1] = bfbits(r1.w); v3[2] = bfbits(r2.w); v3[3] = bfbits(r3.w);
        *(short4x*)&XT[cur ^ 1][4 * h + 0][kof] = v0;
        *(short4x*)&XT[cur ^ 1][4 * h + 1][kof] = v1;
        *(short4x*)&XT[cur ^ 1][4 * h + 2][kof] = v2;
        *(short4x*)&XT[cur ^ 1][4 * h + 3][kof] = v3;
      }
      if (kc + 256 < NQ) {  // prefetch chunk kc+256
#pragma unroll
        for (int i = 0; i < 4; ++i) {
          pf[i]     = *(const float4*)(xsrc + (size_t)(kc + 256 + i) * Cn);
          pf[4 + i] = *(const float4*)(xsrc + (size_t)(kc + 320 + i) * Cn);
        }
      }
    }
#pragma unroll
    for (int kk = 0; kk < 128; kk += 32) {
      const short8 a0 = *(const short8*)(wr0 + kc + kk + q * 8);
      const short8 a1 = *(const short8*)(wr1 + kc + kk + q * 8);
      const short8 b0 = *(const short8*)&XT[cur][ch + lr][(kk + q * 8) ^ swzr0];
      const short8 b1 = *(const short8*)&XT[cur][ch + 16 + lr][(kk + q * 8) ^ swzr1];
      acc[0][0] = MFMA16(a0, b0, acc[0][0]);
      acc[0][1] = MFMA16(a0, b1, acc[0][1]);
      acc[1][0] = MFMA16(a1, b0, acc[1][0]);
      acc[1][1] = MFMA16(a1, b1, acc[1][1]);
    }
  }
  float* pout = part + ((size_t)ks * Bn + b) * Mn * Cn;
#pragma unroll
  for (int mi = 0; mi < 2; ++mi)
#pragma unroll
    for (int ci = 0; ci < 2; ++ci) {
      const int m = mh + mi * 16 + q * 4;
      const int c = cbase + ch + ci * 16 + lr;
#pragma unroll
      for (int reg = 0; reg < 4; ++reg)
        pout[(size_t)(m + reg) * Cn + c] = acc[mi][ci][reg];
    }
}

// ---------------------------------------------------------------------------
// K4: out = sum of 8 partials (float4).  grid 512, block 256
// ---------------------------------------------------------------------------
__global__ __launch_bounds__(256) void reduce_kernel(
    const float* __restrict__ part, float* __restrict__ out) {
  const int i = blockIdx.x * 256 + threadIdx.x;
  const float4* p = (const float4*)part;
  const int S4 = (Bn * Mn * Cn) / 4;
  float4 o = (float4){0.f, 0.f, 0.f, 0.f};
#pragma unroll
  for (int j = 0; j < 8; ++j) {
    const float4 v = p[i + j * S4];
    o.x += v.x; o.y += v.y; o.z += v.z; o.w += v.w;
  }
  ((float4*)out)[i] = o;
}

extern "C" void kernel_launch(void* const* d_in, const int* in_sizes, int n_in,
                              void* d_out, int out_size, void* d_ws, size_t ws_size,
                              hipStream_t stream) {
  const float* x = (const float*)d_in[0];
  const float* W = (const float*)d_in[1];
  const float* bias = (const float*)d_in[2];
  const float* av = (const float*)d_in[3];
  float* out = (float*)d_out;
  char* ws = (char*)d_ws;

  bf16* Vhi = (bf16*)(ws + 0);           // 131072 B
  bf16* Vlo = (bf16*)(ws + 131072);      // 131072 B
  float* c0 = (float*)(ws + 262144);     // 1024 B
  bf16* wgt = (bf16*)(ws + 263168);      // 4194304 B
  // logits (8.4MB, live K1->K2) and part (16.8MB, live K3->K4) time-share
  // one region: stream order guarantees logits is dead before part writes.
  float* logits = (float*)(ws + 4457472);  // 8388608 B
  float* part = (float*)(ws + 4457472);    // 8 x 2097152 B  (total ~21.2 MB)

  prep_kernel<<<dim3(Mn, Cn / 64), 256, 0, stream>>>(W, bias, av, Vhi, Vlo, c0);
  logits_kernel<<<dim3(Nn / 64, Bn), 256, 0, stream>>>(x, Vhi, Vlo, c0, logits);
  softmax_kernel<<<Bn * Mn, 256, 0, stream>>>(logits, wgt);
  pool_kernel<<<dim3(Cn / 64, Bn, 8), 256, 0, stream>>>(x, wgt, part);
  reduce_kernel<<<(Bn * Mn * Cn) / 1024, 256, 0, stream>>>(part, out);
}